// Round 13
// baseline (94.463 us; speedup 1.0000x reference)
//
#include <hip/hip_runtime.h>

#define NATOMS 8192
#define NMOLS  256
#define APM    32
#define EPM    61
#define D      64
#define FIN    16
#define SE     72   // bf16 elems per LDS state row (144B)

typedef __bf16 bf16x8 __attribute__((ext_vector_type(8)));
typedef float  f32x4  __attribute__((ext_vector_type(4)));

#define MFMA_BF16(a, b, c) __builtin_amdgcn_mfma_f32_16x16x32_bf16((a), (b), (c), 0, 0, 0)

__device__ __forceinline__ ushort f2bf(float x) {   // RNE f32 -> bf16
    uint u = __float_as_uint(x);
    u += 0x7fffu + ((u >> 16) & 1u);
    return (ushort)(u >> 16);
}
__device__ __forceinline__ float bf2f(ushort h) {
    return __uint_as_float(((uint)h) << 16);
}
__device__ __forceinline__ void split2(float x, ushort& h, ushort& l) {
    ushort hh = f2bf(x);
    h = hh;
    l = f2bf(x - bf2f(hh));
}
// tanh(x) = 1 - 2/(exp(2x)+1); exp2-based, saturates correctly at +-inf
__device__ __forceinline__ float fast_tanh(float x) {
    float e = __builtin_amdgcn_exp2f(x * 2.885390081777926f);   // exp(2x)
    float r = __builtin_amdgcn_rcpf(e + 1.0f);
    return __builtin_fmaf(-2.0f, r, 1.0f);
}

union FragU { ushort u[8]; bf16x8 v; };

// split-bf16 step with SPLIT lo chains: H += Ah*Wh ; La += Al*Wh ; Lb += Ah*Wl
__device__ __forceinline__ void mfma3s(const ushort* pH, const ushort* pL, int o,
                                       bf16x8 wH, bf16x8 wL,
                                       f32x4& H, f32x4& La, f32x4& Lb) {
    bf16x8 ah = *(const bf16x8*)(pH + o);
    bf16x8 al = *(const bf16x8*)(pL + o);
    H  = MFMA_BF16(ah, wH, H);
    La = MFMA_BF16(al, wH, La);
    Lb = MFMA_BF16(ah, wL, Lb);
}

// 256 threads (4 waves), 2 blocks/CU: redundant block pairs give each CU two
// INDEPENDENT barrier domains -> one block's waves run while the other drains.
__global__ __launch_bounds__(256, 2) void graphnet_kernel(
    const float* __restrict__ atoms,
    const float* __restrict__ adj,
    const int*   __restrict__ left,
    const int*   __restrict__ right,
    const float* __restrict__ Wfe, const float* __restrict__ bfe,
    const float* __restrict__ Wfv, const float* __restrict__ bfv,
    const float* __restrict__ Wfu, const float* __restrict__ bfu,
    const float* __restrict__ Wpe, const float* __restrict__ bpe,
    const float* __restrict__ Wpv, const float* __restrict__ bpv,
    const float* __restrict__ Wpu, const float* __restrict__ bpu,
    float* __restrict__ out)
{
    __shared__ __align__(16) ushort heH[2][64 * SE], heL[2][64 * SE];  // dbuf; rows 61-63 zero
    __shared__ __align__(16) ushort hvH[2][APM * SE], hvL[2][APM * SE];
    __shared__ __align__(16) ushort huH[D], huL[D];
    __shared__ float huF[D], hu0F[D];
    __shared__ float apm_s[FIN];
    __shared__ float parte[4][D];
    __shared__ float part2[2][D];
    __shared__ float hebar[D];
    __shared__ float phiu_part[4][D];
    __shared__ int   lloc[EPM], rloc[EPM];
    __shared__ int   inc[APM][4];              // padded with edge 63 (zero row)

    const int tid  = threadIdx.x;
    const int lane = tid & 63;
    const int w    = tid >> 6;                 // wave 0..3 = N-tile (16-col slice)
    const int cb   = __builtin_amdgcn_readfirstlane(w) * 16;
    const int lr   = lane & 15;
    const int kb   = lane >> 4;
    const int m    = blockIdx.x >> 1;
    const bool writer = (blockIdx.x & 1) == 0;

    // ---------------- init: all LDS writes, no intra-init barriers ----------------
    if (tid < EPM) {
        lloc[tid] = left [m * EPM + tid] - m * APM;
        rloc[tid] = right[m * EPM + tid] - m * APM;
    }
    if (tid < APM) {
        int dg = 0;
        for (int e = 0; e < EPM; ++e) {
            int gl = left [m * EPM + e] - m * APM;   // thread-invariant -> s_load
            int gr = right[m * EPM + e] - m * APM;
            if (gl == tid) inc[tid][dg++] = e;
            if (gr == tid) inc[tid][dg++] = e;
        }
        for (int j = dg; j < 4; ++j) inc[tid][j] = 63;
    }
    if (tid < FIN) {
        float s = 0.f;
        for (int a = 0; a < APM; ++a) s += atoms[(m * APM + a) * FIN + tid];
        apm_s[tid] = s;
    }
    // h_v init (atom row wave-uniform -> scalar loads)
    #pragma unroll
    for (int i = 0; i < 8; ++i) {
        int idx = tid + 256 * i;               // 0..2047
        int a = idx >> 6, c = idx & 63;
        float acc = bfv[c];
        #pragma unroll
        for (int f = 0; f < FIN; ++f)
            acc += atoms[(m * APM + a) * FIN + f] * Wfv[f * D + c];
        float t = fast_tanh(acc);
        ushort h, l; split2(t, h, l);
        hvH[0][a * SE + c] = h; hvL[0][a * SE + c] = l;
    }
    // h_e init (+ zero pad rows 61..63 in BOTH buffers)
    #pragma unroll
    for (int i = 0; i < 16; ++i) {
        int idx = tid + 256 * i;               // 0..4095
        int e = idx >> 6, c = idx & 63;        // e wave-uniform
        float t = 0.f;
        if (e < EPM) {
            int gl = left [m * EPM + e];       // thread-invariant -> s_load
            int gr = right[m * EPM + e];
            float bo = adj[(size_t)gl * NATOMS + gr];
            t = fast_tanh(bo * Wfe[c] + bfe[c]);
        }
        ushort h, l; split2(t, h, l);
        heH[0][e * SE + c] = h; heL[0][e * SE + c] = l;
        if (e >= EPM) { heH[1][e * SE + c] = 0; heL[1][e * SE + c] = 0; }
    }

    // ---------------- persistent weight fragments (s=2,3 transient below) ----------------
    FragU feH[8], feL[8], fvH[8], fvL[8];
    #pragma unroll
    for (int s = 0; s < 8; ++s) {
        if (s == 2 || s == 3) continue;        // constant blocks folded in precompute
        #pragma unroll
        for (int j = 0; j < 8; ++j) {
            split2(Wpe[(s * 32 + kb * 8 + j) * D + cb + lr], feH[s].u[j], feL[s].u[j]);
            split2(Wpv[(s * 32 + kb * 8 + j) * D + cb + lr], fvH[s].u[j], fvL[s].u[j]);
        }
    }
    float wpu_reg[64];                         // wave w owns source block w (64 K-rows)
    #pragma unroll
    for (int kk = 0; kk < 64; ++kk)
        wpu_reg[kk] = Wpu[(w * 64 + kk) * D + lane];
    const float bias_e = bpe[cb + lr];
    const float w5_e   = Wpe[4 * D * D + cb + lr];
    const float bias_v = bpv[cb + lr];
    const float bpu_l  = bpu[lane];

    __syncthreads();                                               // B: all init visible

    // h_u: redundantly in registers per wave (lane = feature)
    float hu_val;
    {
        float acc = bfu[lane];
        #pragma unroll
        for (int f = 0; f < FIN; ++f) acc += apm_s[f] * Wfu[f * D + lane];
        hu_val = fast_tanh(acc);
        if (w == 3) {
            huF[lane] = hu_val; hu0F[lane] = hu_val;
            split2(hu_val, huH[lane], huL[lane]);
        }
    }

    const int col = cb + lr;
    // phi_e row tiles 0..3 (rows t*16+lr); tile 3 rows 61-63 are zero pad
    const int e0 = lr, e1 = 16 + lr, e2 = 32 + lr, e3 = 48 + lr;
    const int ec3 = (e3 < EPM) ? e3 : EPM - 1;
    const int la0 = lloc[e0],  ra0 = rloc[e0];
    const int la1 = lloc[e1],  ra1 = rloc[e1];
    const int la2 = lloc[e2],  ra2 = rloc[e2];
    const int la3 = lloc[ec3], ra3 = rloc[ec3];
    const int ofk = kb * 8;
    // phi_v atom tiles 0..1 (rows at*16+lr)
    const int a0 = lr, a1 = 16 + lr;
    const int i00 = inc[a0][0], i01 = inc[a0][1], i02 = inc[a0][2], i03 = inc[a0][3];
    const int i10 = inc[a1][0], i11 = inc[a1][1], i12 = inc[a1][2], i13 = inc[a1][3];

    // ---------------- loop-invariant contributions (he0@W2, hv0@V2 + biases) ----------------
    f32x4 cE0 = {bias_e, bias_e, bias_e, bias_e};
    f32x4 cE1 = cE0, cE2 = cE0, cE3 = cE0;
    f32x4 cV0 = {bias_v, bias_v, bias_v, bias_v};
    f32x4 cV1 = cV0;
    {
        FragU w2h, w2l, w3h, w3l, v2h, v2l, v3h, v3l;
        #pragma unroll
        for (int j = 0; j < 8; ++j) {
            split2(Wpe[(2 * 32 + kb * 8 + j) * D + cb + lr], w2h.u[j], w2l.u[j]);
            split2(Wpe[(3 * 32 + kb * 8 + j) * D + cb + lr], w3h.u[j], w3l.u[j]);
            split2(Wpv[(2 * 32 + kb * 8 + j) * D + cb + lr], v2h.u[j], v2l.u[j]);
            split2(Wpv[(3 * 32 + kb * 8 + j) * D + cb + lr], v3h.u[j], v3l.u[j]);
        }
        f32x4 z0 = {0,0,0,0}, z1 = {0,0,0,0};
        mfma3s(heH[0] + e0*SE, heL[0] + e0*SE, ofk,      w2h.v, w2l.v, cE0, z0, z1);
        mfma3s(heH[0] + e0*SE, heL[0] + e0*SE, 32 + ofk, w3h.v, w3l.v, cE0, z0, z1);
        cE0 += z0 + z1; z0 = (f32x4){0,0,0,0}; z1 = (f32x4){0,0,0,0};
        mfma3s(heH[0] + e1*SE, heL[0] + e1*SE, ofk,      w2h.v, w2l.v, cE1, z0, z1);
        mfma3s(heH[0] + e1*SE, heL[0] + e1*SE, 32 + ofk, w3h.v, w3l.v, cE1, z0, z1);
        cE1 += z0 + z1; z0 = (f32x4){0,0,0,0}; z1 = (f32x4){0,0,0,0};
        mfma3s(heH[0] + e2*SE, heL[0] + e2*SE, ofk,      w2h.v, w2l.v, cE2, z0, z1);
        mfma3s(heH[0] + e2*SE, heL[0] + e2*SE, 32 + ofk, w3h.v, w3l.v, cE2, z0, z1);
        cE2 += z0 + z1; z0 = (f32x4){0,0,0,0}; z1 = (f32x4){0,0,0,0};
        mfma3s(heH[0] + e3*SE, heL[0] + e3*SE, ofk,      w2h.v, w2l.v, cE3, z0, z1);
        mfma3s(heH[0] + e3*SE, heL[0] + e3*SE, 32 + ofk, w3h.v, w3l.v, cE3, z0, z1);
        cE3 += z0 + z1; z0 = (f32x4){0,0,0,0}; z1 = (f32x4){0,0,0,0};
        mfma3s(hvH[0] + a0*SE, hvL[0] + a0*SE, ofk,      v2h.v, v2l.v, cV0, z0, z1);
        mfma3s(hvH[0] + a0*SE, hvL[0] + a0*SE, 32 + ofk, v3h.v, v3l.v, cV0, z0, z1);
        cV0 += z0 + z1; z0 = (f32x4){0,0,0,0}; z1 = (f32x4){0,0,0,0};
        mfma3s(hvH[0] + a1*SE, hvL[0] + a1*SE, ofk,      v2h.v, v2l.v, cV1, z0, z1);
        mfma3s(hvH[0] + a1*SE, hvL[0] + a1*SE, 32 + ofk, v3h.v, v3l.v, cV1, z0, z1);
        cV1 += z0 + z1;
    }

    // one phi_e tile-pair: 12 units, chains interleaved across the two tiles
#define PHIE_PAIR(EA, LA_, RA_, EB, LB_, RB_, HA, LaA, LbA, HB, LaB, LbB)                    \
    mfma3s(heHc + (EA)*SE,  heLc + (EA)*SE,  ofk,      feH[0].v, feL[0].v, HA, LaA, LbA);    \
    mfma3s(heHc + (EB)*SE,  heLc + (EB)*SE,  ofk,      feH[0].v, feL[0].v, HB, LaB, LbB);    \
    mfma3s(heHc + (EA)*SE,  heLc + (EA)*SE,  32 + ofk, feH[1].v, feL[1].v, HA, LaA, LbA);    \
    mfma3s(heHc + (EB)*SE,  heLc + (EB)*SE,  32 + ofk, feH[1].v, feL[1].v, HB, LaB, LbB);    \
    mfma3s(hvHc + (LA_)*SE, hvLc + (LA_)*SE, ofk,      feH[4].v, feL[4].v, HA, LaA, LbA);    \
    mfma3s(hvHc + (LB_)*SE, hvLc + (LB_)*SE, ofk,      feH[4].v, feL[4].v, HB, LaB, LbB);    \
    mfma3s(hvHc + (LA_)*SE, hvLc + (LA_)*SE, 32 + ofk, feH[5].v, feL[5].v, HA, LaA, LbA);    \
    mfma3s(hvHc + (LB_)*SE, hvLc + (LB_)*SE, 32 + ofk, feH[5].v, feL[5].v, HB, LaB, LbB);    \
    mfma3s(hvHc + (RA_)*SE, hvLc + (RA_)*SE, ofk,      feH[6].v, feL[6].v, HA, LaA, LbA);    \
    mfma3s(hvHc + (RB_)*SE, hvLc + (RB_)*SE, ofk,      feH[6].v, feL[6].v, HB, LaB, LbB);    \
    mfma3s(hvHc + (RA_)*SE, hvLc + (RA_)*SE, 32 + ofk, feH[7].v, feL[7].v, HA, LaA, LbA);    \
    mfma3s(hvHc + (RB_)*SE, hvLc + (RB_)*SE, 32 + ofk, feH[7].v, feL[7].v, HB, LaB, LbB);

    int cur = 0;
    // ---------------- 3 message-passing iterations, 3 barriers each ----------------
    for (int it = 0; it < 3; ++it) {
        const ushort* heHc = heH[cur]; const ushort* heLc = heL[cur];
        const ushort* hvHc = hvH[cur]; const ushort* hvLc = hvL[cur];
        const int nxt = cur ^ 1;

        // ---- phi_e tile pair (0,1) ----
        f32x4 pH0 = cE0, pLa0 = {0,0,0,0}, pLb0 = {0,0,0,0};
        f32x4 pH1 = cE1, pLa1 = {0,0,0,0}, pLb1 = {0,0,0,0};
        PHIE_PAIR(e0, la0, ra0, e1, la1, ra1, pH0, pLa0, pLb0, pH1, pLa1, pLb1);

        // deferred hu finalize (phiu_part D-guarded from prev iter), under MFMAs
        if (it > 0) {
            float t = bpu_l;
            #pragma unroll
            for (int j = 0; j < 4; ++j) t += phiu_part[j][lane];
            hu_val = fast_tanh(t);
            if (w == 3) {
                huF[lane] = hu_val;
                split2(hu_val, huH[lane], huL[lane]);
            }
        }
        float uev = hu_val;
        #pragma unroll
        for (int off = 32; off; off >>= 1) uev += __shfl_xor(uev, off, 64);

        // epilogue pair (0,1): rows 0..31, all valid
        float o0[4], o1[4]; float s0 = 0.f, s1 = 0.f;
        #pragma unroll
        for (int r = 0; r < 4; ++r) {
            float t0 = fast_tanh(pH0[r] + pLa0[r] + pLb0[r] + uev * w5_e);
            float t1 = fast_tanh(pH1[r] + pLa1[r] + pLb1[r] + uev * w5_e);
            o0[r] = t0; o1[r] = t1; s0 += t0; s1 += t1;
        }

        // ---- phi_e tile pair (2,3) ----
        f32x4 pH2 = cE2, pLa2 = {0,0,0,0}, pLb2 = {0,0,0,0};
        f32x4 pH3 = cE3, pLa3 = {0,0,0,0}, pLb3 = {0,0,0,0};
        PHIE_PAIR(e2, la2, ra2, e3, la3, ra3, pH2, pLa2, pLb2, pH3, pLa3, pLb3);

        float o2[4], o3[4]; float s2 = 0.f, s3 = 0.f;
        #pragma unroll
        for (int r = 0; r < 4; ++r) {
            float t2 = fast_tanh(pH2[r] + pLa2[r] + pLb2[r] + uev * w5_e);
            float t3 = fast_tanh(pH3[r] + pLa3[r] + pLb3[r] + uev * w5_e);
            o2[r] = t2; o3[r] = t3; s2 += t2;
            if (48 + kb * 4 + r < EPM) s3 += t3;
        }

        if (it == 2) {                         // final: write output (even blocks), done
            if (writer) {
                #pragma unroll
                for (int r = 0; r < 4; ++r) {
                    int g = kb * 4 + r;
                    out[((size_t)(m * EPM + g)) * D + col] = o0[r];
                    out[((size_t)(m * EPM + g + 16)) * D + col] = o1[r];
                    out[((size_t)(m * EPM + g + 32)) * D + col] = o2[r];
                    if (g + 48 < EPM)
                        out[((size_t)(m * EPM + g + 48)) * D + col] = o3[r];
                }
            }
            return;
        }

        s0 += __shfl_xor(s0, 16, 64); s0 += __shfl_xor(s0, 32, 64);
        s1 += __shfl_xor(s1, 16, 64); s1 += __shfl_xor(s1, 32, 64);
        s2 += __shfl_xor(s2, 16, 64); s2 += __shfl_xor(s2, 32, 64);
        s3 += __shfl_xor(s3, 16, 64); s3 += __shfl_xor(s3, 32, 64);

        #pragma unroll
        for (int r = 0; r < 4; ++r) {
            int g = kb * 4 + r;
            split2(o0[r], heH[nxt][g * SE + col],        heL[nxt][g * SE + col]);
            split2(o1[r], heH[nxt][(g + 16) * SE + col], heL[nxt][(g + 16) * SE + col]);
            split2(o2[r], heH[nxt][(g + 32) * SE + col], heL[nxt][(g + 32) * SE + col]);
            if (g + 48 < EPM)
                split2(o3[r], heH[nxt][(g + 48) * SE + col], heL[nxt][(g + 48) * SE + col]);
        }
        if (kb == 0) {
            parte[0][col] = s0; parte[1][col] = s1;
            parte[2][col] = s2; parte[3][col] = s3;
        }
        __syncthreads();                                           // A: new he ready

        // ---- phi_v: 2 atom tiles, hbi inlined via linearity; chains split 6+6 ----
        const ushort* heHn = heH[nxt]; const ushort* heLn = heL[nxt];

        // tile 0 (rows 0..15)
        {
            f32x4 vH  = cV0,       vLa  = {0,0,0,0}, vLb  = {0,0,0,0};
            f32x4 vH2 = {0,0,0,0}, vLa2 = {0,0,0,0}, vLb2 = {0,0,0,0};
            mfma3s(hvHc + a0*SE, hvLc + a0*SE, ofk,      fvH[0].v, fvL[0].v, vH, vLa, vLb);
            mfma3s(hvHc + a0*SE, hvLc + a0*SE, 32 + ofk, fvH[1].v, fvL[1].v, vH, vLa, vLb);
            mfma3s(heHn + i00*SE, heLn + i00*SE, ofk,      fvH[4].v, fvL[4].v, vH, vLa, vLb);
            mfma3s(heHn + i00*SE, heLn + i00*SE, 32 + ofk, fvH[5].v, fvL[5].v, vH, vLa, vLb);
            mfma3s(heHn + i01*SE, heLn + i01*SE, ofk,      fvH[4].v, fvL[4].v, vH, vLa, vLb);
            mfma3s(heHn + i01*SE, heLn + i01*SE, 32 + ofk, fvH[5].v, fvL[5].v, vH, vLa, vLb);
            mfma3s(heHn + i02*SE, heLn + i02*SE, ofk,      fvH[4].v, fvL[4].v, vH2, vLa2, vLb2);
            mfma3s(heHn + i02*SE, heLn + i02*SE, 32 + ofk, fvH[5].v, fvL[5].v, vH2, vLa2, vLb2);
            mfma3s(heHn + i03*SE, heLn + i03*SE, ofk,      fvH[4].v, fvL[4].v, vH2, vLa2, vLb2);
            mfma3s(heHn + i03*SE, heLn + i03*SE, 32 + ofk, fvH[5].v, fvL[5].v, vH2, vLa2, vLb2);
            mfma3s(huH, huL, ofk,      fvH[6].v, fvL[6].v, vH2, vLa2, vLb2);
            mfma3s(huH, huL, 32 + ofk, fvH[7].v, fvL[7].v, vH2, vLa2, vLb2);

            if (tid < D)   // hebar reduce (readers are post-C), under the MFMA block
                hebar[tid] = parte[0][tid] + parte[1][tid] + parte[2][tid] + parte[3][tid];

            float ov[4]; float ps = 0.f;
            #pragma unroll
            for (int r = 0; r < 4; ++r) {
                float t = fast_tanh((vH[r] + vH2[r]) + (vLa[r] + vLa2[r]) + (vLb[r] + vLb2[r]));
                ov[r] = t; ps += t;
            }
            ps += __shfl_xor(ps, 16, 64); ps += __shfl_xor(ps, 32, 64);
            #pragma unroll
            for (int r = 0; r < 4; ++r) {
                int g = kb * 4 + r;
                split2(ov[r], hvH[nxt][g * SE + col], hvL[nxt][g * SE + col]);
            }
            if (kb == 0) part2[0][col] = ps;
        }
        // tile 1 (rows 16..31)
        {
            f32x4 vH  = cV1,       vLa  = {0,0,0,0}, vLb  = {0,0,0,0};
            f32x4 vH2 = {0,0,0,0}, vLa2 = {0,0,0,0}, vLb2 = {0,0,0,0};
            mfma3s(hvHc + a1*SE, hvLc + a1*SE, ofk,      fvH[0].v, fvL[0].v, vH, vLa, vLb);
            mfma3s(hvHc + a1*SE, hvLc + a1*SE, 32 + ofk, fvH[1].v, fvL[1].v, vH, vLa, vLb);
            mfma3s(heHn + i10*SE, heLn + i10*SE, ofk,      fvH[4].v, fvL[4].v, vH, vLa, vLb);
            mfma3s(heHn + i10*SE, heLn + i10*SE, 32 + ofk, fvH[5].v, fvL[5].v, vH, vLa, vLb);
            mfma3s(heHn + i11*SE, heLn + i11*SE, ofk,      fvH[4].v, fvL[4].v, vH, vLa, vLb);
            mfma3s(heHn + i11*SE, heLn + i11*SE, 32 + ofk, fvH[5].v, fvL[5].v, vH, vLa, vLb);
            mfma3s(heHn + i12*SE, heLn + i12*SE, ofk,      fvH[4].v, fvL[4].v, vH2, vLa2, vLb2);
            mfma3s(heHn + i12*SE, heLn + i12*SE, 32 + ofk, fvH[5].v, fvL[5].v, vH2, vLa2, vLb2);
            mfma3s(heHn + i13*SE, heLn + i13*SE, ofk,      fvH[4].v, fvL[4].v, vH2, vLa2, vLb2);
            mfma3s(heHn + i13*SE, heLn + i13*SE, 32 + ofk, fvH[5].v, fvL[5].v, vH2, vLa2, vLb2);
            mfma3s(huH, huL, ofk,      fvH[6].v, fvL[6].v, vH2, vLa2, vLb2);
            mfma3s(huH, huL, 32 + ofk, fvH[7].v, fvL[7].v, vH2, vLa2, vLb2);

            float ov[4]; float ps = 0.f;
            #pragma unroll
            for (int r = 0; r < 4; ++r) {
                float t = fast_tanh((vH[r] + vH2[r]) + (vLa[r] + vLa2[r]) + (vLb[r] + vLb2[r]));
                ov[r] = t; ps += t;
            }
            ps += __shfl_xor(ps, 16, 64); ps += __shfl_xor(ps, 32, 64);
            #pragma unroll
            for (int r = 0; r < 4; ++r) {
                int g = 16 + kb * 4 + r;
                split2(ov[r], hvH[nxt][g * SE + col], hvL[nxt][g * SE + col]);
            }
            if (kb == 0) part2[1][col] = ps;
        }
        __syncthreads();                                           // C: hv' + part2 + hebar ready

        // ---- phi_u partials: wave w owns source block w (64 K-rows) ----
        {
            float s = 0.f;
            #pragma unroll
            for (int kk = 0; kk < 64; ++kk) {
                float x = (w == 0) ? huF[kk] : (w == 1) ? hu0F[kk]
                        : (w == 2) ? hebar[kk] : (part2[0][kk] + part2[1][kk]);
                s += x * wpu_reg[kk];
            }
            phiu_part[w][lane] = s;
        }
        __syncthreads();                                           // D: phiu_part ready
        cur = nxt;                             // hu finalize deferred to next iter
    }
}

extern "C" void kernel_launch(void* const* d_in, const int* in_sizes, int n_in,
                              void* d_out, int out_size, void* d_ws, size_t ws_size,
                              hipStream_t stream) {
    const float* atoms = (const float*)d_in[0];
    const float* adj   = (const float*)d_in[1];
    const int*   left  = (const int*)  d_in[2];
    const int*   right = (const int*)  d_in[3];
    const float* Wfe = (const float*)d_in[6];
    const float* bfe = (const float*)d_in[7];
    const float* Wfv = (const float*)d_in[8];
    const float* bfv = (const float*)d_in[9];
    const float* Wfu = (const float*)d_in[10];
    const float* bfu = (const float*)d_in[11];
    const float* Wpe = (const float*)d_in[12];
    const float* bpe = (const float*)d_in[13];
    const float* Wpv = (const float*)d_in[14];
    const float* bpv = (const float*)d_in[15];
    const float* Wpu = (const float*)d_in[16];
    const float* bpu = (const float*)d_in[17];

    // 2 blocks per molecule (redundant pair) -> 2 independent sync domains per CU
    graphnet_kernel<<<dim3(NMOLS * 2), dim3(256), 0, stream>>>(
        atoms, adj, left, right,
        Wfe, bfe, Wfv, bfv, Wfu, bfu,
        Wpe, bpe, Wpv, bpv, Wpu, bpu,
        (float*)d_out);
}

// Round 14
// 34.900 us; speedup vs baseline: 2.7066x; 2.7066x over previous
//
#include <hip/hip_runtime.h>

#define NATOMS 8192
#define NMOLS  256
#define APM    32
#define EPM    61
#define D      64
#define FIN    16
#define SE     72   // bf16 elems per LDS state row (144B)

typedef __bf16 bf16x8 __attribute__((ext_vector_type(8)));
typedef float  f32x4  __attribute__((ext_vector_type(4)));

#define MFMA_BF16(a, b, c) __builtin_amdgcn_mfma_f32_16x16x32_bf16((a), (b), (c), 0, 0, 0)

__device__ __forceinline__ ushort f2bf(float x) {   // RNE f32 -> bf16
    uint u = __float_as_uint(x);
    u += 0x7fffu + ((u >> 16) & 1u);
    return (ushort)(u >> 16);
}
__device__ __forceinline__ float bf2f(ushort h) {
    return __uint_as_float(((uint)h) << 16);
}
__device__ __forceinline__ void split2(float x, ushort& h, ushort& l) {
    ushort hh = f2bf(x);
    h = hh;
    l = f2bf(x - bf2f(hh));
}
// tanh(x) = 1 - 2/(exp(2x)+1); exp2-based, saturates correctly at +-inf
__device__ __forceinline__ float fast_tanh(float x) {
    float e = __builtin_amdgcn_exp2f(x * 2.885390081777926f);   // exp(2x)
    float r = __builtin_amdgcn_rcpf(e + 1.0f);
    return __builtin_fmaf(-2.0f, r, 1.0f);
}

union FragU { ushort u[8]; bf16x8 v; };

// split-bf16 step with SPLIT lo chains: H += Ah*Wh ; La += Al*Wh ; Lb += Ah*Wl
__device__ __forceinline__ void mfma3s(const ushort* pH, const ushort* pL, int o,
                                       bf16x8 wH, bf16x8 wL,
                                       f32x4& H, f32x4& La, f32x4& Lb) {
    bf16x8 ah = *(const bf16x8*)(pH + o);
    bf16x8 al = *(const bf16x8*)(pL + o);
    H  = MFMA_BF16(ah, wH, H);
    La = MFMA_BF16(al, wH, La);
    Lb = MFMA_BF16(ah, wL, Lb);
}

__global__ __launch_bounds__(512, 2) void graphnet_kernel(
    const float* __restrict__ atoms,
    const float* __restrict__ adj,
    const int*   __restrict__ left,
    const int*   __restrict__ right,
    const float* __restrict__ Wfe, const float* __restrict__ bfe,
    const float* __restrict__ Wfv, const float* __restrict__ bfv,
    const float* __restrict__ Wfu, const float* __restrict__ bfu,
    const float* __restrict__ Wpe, const float* __restrict__ bpe,
    const float* __restrict__ Wpv, const float* __restrict__ bpv,
    const float* __restrict__ Wpu, const float* __restrict__ bpu,
    float* __restrict__ out)
{
    __shared__ __align__(16) ushort heH[2][64 * SE], heL[2][64 * SE];  // dbuf; rows 61-63 zero
    __shared__ __align__(16) ushort hvH[2][APM * SE], hvL[2][APM * SE];
    __shared__ __align__(16) ushort huH[D], huL[D];
    __shared__ float huF[D], hu0F[D];
    __shared__ float apm_s[FIN];
    __shared__ float parte[4][D];
    __shared__ float part2[2][D];
    __shared__ float hebar[D];
    __shared__ float phiu_part[8][D];
    __shared__ int   lloc[EPM], rloc[EPM];
    __shared__ int   inc[APM][4];              // padded with edge 63 (zero row)

    const int tid  = threadIdx.x;
    const int lane = tid & 63;
    const int w    = tid >> 6;                 // wave 0..7
    const int nt   = w & 3;                    // N-tile (16-col slice)
    const int mt2  = w >> 2;                   // 0..1
    const int cb   = __builtin_amdgcn_readfirstlane(nt) * 16;
    const int lr   = lane & 15;
    const int kb   = lane >> 4;
    const int m    = blockIdx.x;

    // ---------------- init: all LDS writes, no intra-init barriers ----------------
    if (tid < EPM) {
        lloc[tid] = left [m * EPM + tid] - m * APM;
        rloc[tid] = right[m * EPM + tid] - m * APM;
    }
    // incidence lists from wave-uniform global reads (padded to 4 with zero-row 63)
    if (tid < APM) {
        int dg = 0;
        for (int e = 0; e < EPM; ++e) {
            int gl = left [m * EPM + e] - m * APM;   // thread-invariant -> s_load
            int gr = right[m * EPM + e] - m * APM;
            if (gl == tid) inc[tid][dg++] = e;
            if (gr == tid) inc[tid][dg++] = e;
        }
        for (int j = dg; j < 4; ++j) inc[tid][j] = 63;
    }
    if (tid < FIN) {
        float s = 0.f;
        for (int a = 0; a < APM; ++a) s += atoms[(m * APM + a) * FIN + tid];
        apm_s[tid] = s;
    }
    // h_v init (atom row wave-uniform -> scalar loads)
    #pragma unroll
    for (int i = 0; i < 4; ++i) {
        int idx = tid + 512 * i;               // 0..2047
        int a = idx >> 6, c = idx & 63;
        float acc = bfv[c];
        #pragma unroll
        for (int f = 0; f < FIN; ++f)
            acc += atoms[(m * APM + a) * FIN + f] * Wfv[f * D + c];
        float t = fast_tanh(acc);
        ushort h, l; split2(t, h, l);
        hvH[0][a * SE + c] = h; hvL[0][a * SE + c] = l;
    }
    // h_e init (+ zero pad rows 61..63 in BOTH buffers)
    #pragma unroll
    for (int i = 0; i < 8; ++i) {
        int idx = tid + 512 * i;               // 0..4095
        int e = idx >> 6, c = idx & 63;        // e wave-uniform
        float t = 0.f;
        if (e < EPM) {
            int gl = left [m * EPM + e];       // thread-invariant -> s_load
            int gr = right[m * EPM + e];
            float bo = adj[(size_t)gl * NATOMS + gr];
            t = fast_tanh(bo * Wfe[c] + bfe[c]);
        }
        ushort h, l; split2(t, h, l);
        heH[0][e * SE + c] = h; heL[0][e * SE + c] = l;
        if (e >= EPM) { heH[1][e * SE + c] = 0; heL[1][e * SE + c] = 0; }
    }

    // ---------------- persistent weight fragments (s=2,3 transient below) ----------------
    FragU feH[8], feL[8], fvH[8], fvL[8];
    #pragma unroll
    for (int s = 0; s < 8; ++s) {
        if (s == 2 || s == 3) continue;        // constant blocks folded in precompute
        #pragma unroll
        for (int j = 0; j < 8; ++j) {
            split2(Wpe[(s * 32 + kb * 8 + j) * D + cb + lr], feH[s].u[j], feL[s].u[j]);
            split2(Wpv[(s * 32 + kb * 8 + j) * D + cb + lr], fvH[s].u[j], fvL[s].u[j]);
        }
    }
    float wpu_reg[32];
    #pragma unroll
    for (int kk = 0; kk < 32; ++kk)
        wpu_reg[kk] = Wpu[(w * 32 + kk) * D + lane];
    const float bias_e = bpe[cb + lr];
    const float w5_e   = Wpe[4 * D * D + cb + lr];
    const float bias_v = bpv[cb + lr];
    const float bpu_l  = bpu[lane];

    __syncthreads();                                               // B: all init visible

    // h_u: redundantly in registers per wave (lane = feature)
    float hu_val;
    {
        float acc = bfu[lane];
        #pragma unroll
        for (int f = 0; f < FIN; ++f) acc += apm_s[f] * Wfu[f * D + lane];
        hu_val = fast_tanh(acc);
        if (w == 7) {
            huF[lane] = hu_val; hu0F[lane] = hu_val;
            split2(hu_val, huH[lane], huL[lane]);
        }
    }

    const int col  = cb + lr;
    const int e0   = mt2 * 16 + lr;
    const int e1   = e0 + 32;
    const int ec1  = (e1 < EPM) ? e1 : EPM - 1;
    const int la0  = lloc[e0],  ra0 = rloc[e0];
    const int la1  = lloc[ec1], ra1 = rloc[ec1];
    const int ofk  = kb * 8;
    const int arow = mt2 * 16 + lr;
    const int ie0 = inc[arow][0], ie1 = inc[arow][1];
    const int ie2 = inc[arow][2], ie3 = inc[arow][3];

    // ---------------- loop-invariant contributions (he0@W2, hv0@V2 + biases) ----------------
    f32x4 cE0 = {bias_e, bias_e, bias_e, bias_e};
    f32x4 cE1 = cE0;
    f32x4 cV  = {bias_v, bias_v, bias_v, bias_v};
    {
        FragU w2h, w2l, w3h, w3l, v2h, v2l, v3h, v3l;
        #pragma unroll
        for (int j = 0; j < 8; ++j) {
            split2(Wpe[(2 * 32 + kb * 8 + j) * D + cb + lr], w2h.u[j], w2l.u[j]);
            split2(Wpe[(3 * 32 + kb * 8 + j) * D + cb + lr], w3h.u[j], w3l.u[j]);
            split2(Wpv[(2 * 32 + kb * 8 + j) * D + cb + lr], v2h.u[j], v2l.u[j]);
            split2(Wpv[(3 * 32 + kb * 8 + j) * D + cb + lr], v3h.u[j], v3l.u[j]);
        }
        f32x4 z0 = {0,0,0,0}, z1 = {0,0,0,0}, z2 = {0,0,0,0},
              z3 = {0,0,0,0}, z4 = {0,0,0,0}, z5 = {0,0,0,0};
        mfma3s(heH[0] + e0*SE,  heL[0] + e0*SE,  ofk,      w2h.v, w2l.v, cE0, z0, z1);
        mfma3s(heH[0] + e1*SE,  heL[0] + e1*SE,  ofk,      w2h.v, w2l.v, cE1, z2, z3);
        mfma3s(heH[0] + e0*SE,  heL[0] + e0*SE,  32 + ofk, w3h.v, w3l.v, cE0, z0, z1);
        mfma3s(heH[0] + e1*SE,  heL[0] + e1*SE,  32 + ofk, w3h.v, w3l.v, cE1, z2, z3);
        mfma3s(hvH[0] + arow*SE, hvL[0] + arow*SE, ofk,      v2h.v, v2l.v, cV, z4, z5);
        mfma3s(hvH[0] + arow*SE, hvL[0] + arow*SE, 32 + ofk, v3h.v, v3l.v, cV, z4, z5);
        cE0 += z0 + z1; cE1 += z2 + z3; cV += z4 + z5;
    }

    int cur = 0;
    // ---------------- 3 message-passing iterations, 3 barriers each ----------------
    for (int it = 0; it < 3; ++it) {
        const ushort* heHc = heH[cur]; const ushort* heLc = heL[cur];
        const ushort* hvHc = hvH[cur]; const ushort* hvLc = hvL[cur];

        // ---- phi_e MFMA block: 12 units (he0 term folded into cE0/cE1) ----
        f32x4 aH0 = cE0, aL0a = {0,0,0,0}, aL0b = {0,0,0,0};
        f32x4 aH1 = cE1, aL1a = {0,0,0,0}, aL1b = {0,0,0,0};
        mfma3s(heHc + e0*SE,  heLc + e0*SE,  ofk,      feH[0].v, feL[0].v, aH0, aL0a, aL0b);
        mfma3s(heHc + e1*SE,  heLc + e1*SE,  ofk,      feH[0].v, feL[0].v, aH1, aL1a, aL1b);
        mfma3s(heHc + e0*SE,  heLc + e0*SE,  32 + ofk, feH[1].v, feL[1].v, aH0, aL0a, aL0b);
        mfma3s(heHc + e1*SE,  heLc + e1*SE,  32 + ofk, feH[1].v, feL[1].v, aH1, aL1a, aL1b);
        mfma3s(hvHc + la0*SE, hvLc + la0*SE, ofk,      feH[4].v, feL[4].v, aH0, aL0a, aL0b);
        mfma3s(hvHc + la1*SE, hvLc + la1*SE, ofk,      feH[4].v, feL[4].v, aH1, aL1a, aL1b);
        mfma3s(hvHc + la0*SE, hvLc + la0*SE, 32 + ofk, feH[5].v, feL[5].v, aH0, aL0a, aL0b);
        mfma3s(hvHc + la1*SE, hvLc + la1*SE, 32 + ofk, feH[5].v, feL[5].v, aH1, aL1a, aL1b);
        mfma3s(hvHc + ra0*SE, hvLc + ra0*SE, ofk,      feH[6].v, feL[6].v, aH0, aL0a, aL0b);
        mfma3s(hvHc + ra1*SE, hvLc + ra1*SE, ofk,      feH[6].v, feL[6].v, aH1, aL1a, aL1b);
        mfma3s(hvHc + ra0*SE, hvLc + ra0*SE, 32 + ofk, feH[7].v, feL[7].v, aH0, aL0a, aL0b);
        mfma3s(hvHc + ra1*SE, hvLc + ra1*SE, 32 + ofk, feH[7].v, feL[7].v, aH1, aL1a, aL1b);

        // ---- deferred hu finalize (phiu_part D-guarded from prev iter),
        //      hidden under the MFMA block above ----
        if (it > 0) {
            float t = bpu_l;
            #pragma unroll
            for (int w8 = 0; w8 < 8; ++w8) t += phiu_part[w8][lane];
            hu_val = fast_tanh(t);
            if (w == 7) {
                huF[lane] = hu_val;
                split2(hu_val, huH[lane], huL[lane]);
            }
        }
        // u_e = sum(h_u): register butterfly
        float uev = hu_val;
        #pragma unroll
        for (int off = 32; off; off >>= 1) uev += __shfl_xor(uev, off, 64);

        // ---- phi_e epilogue (bias folded into constants) ----
        float out0[4], out1[4]; float ps0 = 0.f, ps1 = 0.f;
        #pragma unroll
        for (int r = 0; r < 4; ++r) {
            float t0 = fast_tanh(aH0[r] + aL0a[r] + aL0b[r] + uev * w5_e);
            float t1 = fast_tanh(aH1[r] + aL1a[r] + aL1b[r] + uev * w5_e);
            out0[r] = t0; out1[r] = t1;
            ps0 += t0;
            if (32 + mt2 * 16 + kb * 4 + r < EPM) ps1 += t1;
        }

        if (it == 2) {                         // final: write output, done
            #pragma unroll
            for (int r = 0; r < 4; ++r) {
                int g0 = mt2 * 16 + kb * 4 + r;
                out[((size_t)(m * EPM + g0)) * D + col] = out0[r];
                int g1 = g0 + 32;
                if (g1 < EPM) out[((size_t)(m * EPM + g1)) * D + col] = out1[r];
            }
            return;
        }

        ps0 += __shfl_xor(ps0, 16, 64); ps0 += __shfl_xor(ps0, 32, 64);
        ps1 += __shfl_xor(ps1, 16, 64); ps1 += __shfl_xor(ps1, 32, 64);

        const int nxt = cur ^ 1;
        #pragma unroll
        for (int r = 0; r < 4; ++r) {
            int g0 = mt2 * 16 + kb * 4 + r;
            split2(out0[r], heH[nxt][g0 * SE + col], heL[nxt][g0 * SE + col]);
            int g1 = g0 + 32;
            if (g1 < EPM)
                split2(out1[r], heH[nxt][g1 * SE + col], heL[nxt][g1 * SE + col]);
        }
        if (kb == 0) { parte[mt2][col] = ps0; parte[2 + mt2][col] = ps1; }
        __syncthreads();                                           // A: new he ready

        // ---- phi_v: 12 units, hbi inlined via linearity; chains split 6+6 ----
        const ushort* heHn = heH[nxt]; const ushort* heLn = heL[nxt];

        f32x4 vH  = cV,        vLa  = {0,0,0,0}, vLb  = {0,0,0,0};
        f32x4 vH2 = {0,0,0,0}, vLa2 = {0,0,0,0}, vLb2 = {0,0,0,0};
        mfma3s(hvHc + arow*SE, hvLc + arow*SE, ofk,      fvH[0].v, fvL[0].v, vH, vLa, vLb);
        mfma3s(hvHc + arow*SE, hvLc + arow*SE, 32 + ofk, fvH[1].v, fvL[1].v, vH, vLa, vLb);
        mfma3s(heHn + ie0*SE, heLn + ie0*SE, ofk,      fvH[4].v, fvL[4].v, vH, vLa, vLb);
        mfma3s(heHn + ie0*SE, heLn + ie0*SE, 32 + ofk, fvH[5].v, fvL[5].v, vH, vLa, vLb);
        mfma3s(heHn + ie1*SE, heLn + ie1*SE, ofk,      fvH[4].v, fvL[4].v, vH, vLa, vLb);
        mfma3s(heHn + ie1*SE, heLn + ie1*SE, 32 + ofk, fvH[5].v, fvL[5].v, vH, vLa, vLb);
        mfma3s(heHn + ie2*SE, heLn + ie2*SE, ofk,      fvH[4].v, fvL[4].v, vH2, vLa2, vLb2);
        mfma3s(heHn + ie2*SE, heLn + ie2*SE, 32 + ofk, fvH[5].v, fvL[5].v, vH2, vLa2, vLb2);
        mfma3s(heHn + ie3*SE, heLn + ie3*SE, ofk,      fvH[4].v, fvL[4].v, vH2, vLa2, vLb2);
        mfma3s(heHn + ie3*SE, heLn + ie3*SE, 32 + ofk, fvH[5].v, fvL[5].v, vH2, vLa2, vLb2);
        mfma3s(huH, huL, ofk,      fvH[6].v, fvL[6].v, vH2, vLa2, vLb2);
        mfma3s(huH, huL, 32 + ofk, fvH[7].v, fvL[7].v, vH2, vLa2, vLb2);

        if (tid < D)   // hebar reduce (readers are post-C), under the MFMA block
            hebar[tid] = parte[0][tid] + parte[1][tid] + parte[2][tid] + parte[3][tid];

        float outv2[4]; float ps2 = 0.f;
        #pragma unroll
        for (int r = 0; r < 4; ++r) {
            float t = fast_tanh((vH[r] + vH2[r]) + (vLa[r] + vLa2[r]) + (vLb[r] + vLb2[r]));
            outv2[r] = t; ps2 += t;
        }
        ps2 += __shfl_xor(ps2, 16, 64); ps2 += __shfl_xor(ps2, 32, 64);
        #pragma unroll
        for (int r = 0; r < 4; ++r) {
            int g = mt2 * 16 + kb * 4 + r;
            split2(outv2[r], hvH[nxt][g * SE + col], hvL[nxt][g * SE + col]);
        }
        if (kb == 0) part2[mt2][col] = ps2;
        __syncthreads();                                           // C: hv' + part2 ready

        // ---- phi_u partials: wave w owns K rows [w*32, w*32+32) ----
        {
            const int b  = w >> 1;             // source block (wave-uniform)
            const int k0 = (w & 1) * 32;
            float s = 0.f;
            #pragma unroll
            for (int kk = 0; kk < 32; ++kk) {
                int k = k0 + kk;
                float x = (b == 0) ? huF[k] : (b == 1) ? hu0F[k]
                        : (b == 2) ? hebar[k] : (part2[0][k] + part2[1][k]);
                s += x * wpu_reg[kk];
            }
            phiu_part[w][lane] = s;
        }
        __syncthreads();                                           // D: phiu_part ready
        cur = nxt;                             // hu finalize deferred to next iter
    }
}

extern "C" void kernel_launch(void* const* d_in, const int* in_sizes, int n_in,
                              void* d_out, int out_size, void* d_ws, size_t ws_size,
                              hipStream_t stream) {
    const float* atoms = (const float*)d_in[0];
    const float* adj   = (const float*)d_in[1];
    const int*   left  = (const int*)  d_in[2];
    const int*   right = (const int*)  d_in[3];
    const float* Wfe = (const float*)d_in[6];
    const float* bfe = (const float*)d_in[7];
    const float* Wfv = (const float*)d_in[8];
    const float* bfv = (const float*)d_in[9];
    const float* Wfu = (const float*)d_in[10];
    const float* bfu = (const float*)d_in[11];
    const float* Wpe = (const float*)d_in[12];
    const float* bpe = (const float*)d_in[13];
    const float* Wpv = (const float*)d_in[14];
    const float* bpv = (const float*)d_in[15];
    const float* Wpu = (const float*)d_in[16];
    const float* bpu = (const float*)d_in[17];

    graphnet_kernel<<<dim3(NMOLS), dim3(512), 0, stream>>>(
        atoms, adj, left, right,
        Wfe, bfe, Wfv, bfv, Wfu, bfu,
        Wpe, bpe, Wpv, bpv, Wpu, bpu,
        (float*)d_out);
}